// Round 8
// baseline (158.727 us; speedup 1.0000x reference)
//
#include <hip/hip_runtime.h>
#include <math.h>

#define IN_DIM 256
#define HD     512   // NUM_HEADS * OUT_DIM
#define NHEADS 8
#define DH     64
#define NSEQ   1024
#define BATCH  8

#define QSCALE 0.18033688011112042f   // 0.125 * log2(e): S comes out in log2 domain

typedef unsigned short u16;
typedef unsigned int   u32;
typedef unsigned long long u64;
typedef short bf16x8 __attribute__((ext_vector_type(8)));
typedef float f32x4  __attribute__((ext_vector_type(4)));

#if __has_builtin(__builtin_amdgcn_exp2f)
#define EXP2(x) __builtin_amdgcn_exp2f(x)
#else
#define EXP2(x) __expf(0.69314718056f * (x))
#endif

static __device__ __forceinline__ u16 f2bf(float x) {
    u32 u = __builtin_bit_cast(u32, x);
    u += 0x7FFFu + ((u >> 16) & 1u);     // RNE
    return (u16)(u >> 16);
}
static __device__ __forceinline__ float bf2f(u16 x) {
    return __builtin_bit_cast(float, ((u32)x) << 16);
}
static __device__ __forceinline__ u32 pk(u16 a, u16 b) {
    return (u32)a | ((u32)b << 16);
}
static __device__ __forceinline__ u32 cvtpk(float a, float b) {
    return pk(f2bf(a), f2bf(b));
}

// ============================================================
// Prep (352 blocks):
//  blocks [0,96):   W [K=256][N=512] fp32 -> Wt [N][K] bf16 (x3)
//  blocks [96,352): adj -> MaddT[key][q] bf16 {0, -3.39e38}
// ============================================================
__global__ __launch_bounds__(256)
void prep_kernel(const float* __restrict__ Wq, const float* __restrict__ Wk,
                 const float* __restrict__ Wv, const int* __restrict__ adj,
                 u16* __restrict__ Wt, u16* __restrict__ MaddT)
{
    __shared__ u32 shpool[64 * 65];
    const int bid = blockIdx.x, tid = threadIdx.x;

    if (bid < 96) {
        // ---- weight transpose ----
        float* tile = (float*)shpool;        // [64][65]
        const int wk = bid;
        const int k0 = (wk & 3) * 64, n0 = ((wk >> 2) & 7) * 64, wsel = wk >> 5;
        const float* W = (wsel == 0) ? Wq : (wsel == 1) ? Wk : Wv;
        u16* Out = Wt + (size_t)wsel * HD * IN_DIM;

        const int r = tid >> 2, c0 = (tid & 3) * 16;
#pragma unroll
        for (int j = 0; j < 16; j += 4) {
            float4 v = *(const float4*)(W + (size_t)(k0 + r) * HD + n0 + c0 + j);
            tile[r * 65 + c0 + j + 0] = v.x; tile[r * 65 + c0 + j + 1] = v.y;
            tile[r * 65 + c0 + j + 2] = v.z; tile[r * 65 + c0 + j + 3] = v.w;
        }
        __syncthreads();
        const int n = tid >> 2, ks = (tid & 3) * 16;
        u16 o[16];
#pragma unroll
        for (int j = 0; j < 16; ++j) o[j] = f2bf(tile[(ks + j) * 65 + n]);
        uint4 u0, u1;
        u0.x = pk(o[0], o[1]);   u0.y = pk(o[2], o[3]);
        u0.z = pk(o[4], o[5]);   u0.w = pk(o[6], o[7]);
        u1.x = pk(o[8], o[9]);   u1.y = pk(o[10], o[11]);
        u1.z = pk(o[12], o[13]); u1.w = pk(o[14], o[15]);
        u16* dst = Out + (size_t)(n0 + n) * IN_DIM + k0 + ks;
        *(uint4*)(dst) = u0;
        *(uint4*)(dst + 8) = u1;
    } else {
        // ---- adjacency transpose to bf16 additive mask ----
        int* tile = (int*)shpool;            // [64][65]
        const int abid = bid - 96;
        const int tR = abid >> 4, tC = abid & 15;   // q-tile, k-tile
        const int r = tid >> 2, cg = (tid & 3) * 16;
        const int* src = adj + (size_t)(tR * 64 + r) * NSEQ + tC * 64 + cg;
#pragma unroll
        for (int j = 0; j < 16; j += 4) {
            int4 a = *(const int4*)(src + j);
            tile[r * 65 + cg + j + 0] = a.x; tile[r * 65 + cg + j + 1] = a.y;
            tile[r * 65 + cg + j + 2] = a.z; tile[r * 65 + cg + j + 3] = a.w;
        }
        __syncthreads();
        const int kk = tid >> 2, qg = (tid & 3) * 16;
        u16 o[16];
#pragma unroll
        for (int j = 0; j < 16; ++j)
            o[j] = (tile[(qg + j) * 65 + kk] == 0) ? (u16)0xFF7F : (u16)0;
        uint4 u0, u1;
        u0.x = pk(o[0], o[1]);   u0.y = pk(o[2], o[3]);
        u0.z = pk(o[4], o[5]);   u0.w = pk(o[6], o[7]);
        u1.x = pk(o[8], o[9]);   u1.y = pk(o[10], o[11]);
        u1.z = pk(o[12], o[13]); u1.w = pk(o[14], o[15]);
        u16* dst = MaddT + (size_t)(tC * 64 + kk) * NSEQ + tR * 64 + qg;
        *(uint4*)(dst) = u0;
        *(uint4*)(dst + 8) = u1;
    }
}

// ============================================================
// Fused QKV GEMM: grid (64 m-tiles, 8 heads), 256 thr (4 waves).
// A (fp32 h -> bf16) staged once/k-step; 3 B-tiles; 48 MFMA/k-step.
// Register prefetch of next k-tile hides global latency under MFMA.
// Q pre-scaled by QSCALE; V transposed+chunk-permuted:
// Vt[b][h][d][ch*64+pos(m)], pos(m) = (m&15)*4 + (m>>4).
// ============================================================
__global__ __launch_bounds__(256, 2)
void qkv_gemm_kernel(const float* __restrict__ h, const u16* __restrict__ Wt,
                     const float* __restrict__ bq, const float* __restrict__ bk,
                     const float* __restrict__ bv,
                     u16* __restrict__ Qg, u16* __restrict__ Kg,
                     u16* __restrict__ Vtg)
{
    __shared__ u16 pool[128 * 64 + 3 * 64 * 64];   // As | Bs[3]; epilogue reuse
    u16* As = pool;
    u16* Bs = pool + 128 * 64;

    const int m0 = blockIdx.x * 128;
    const int hh = blockIdx.y;
    const int n0 = hh * 64;

    const int tid = threadIdx.x;
    const int w = tid >> 6, lane = tid & 63, l15 = lane & 15, quad = lane >> 4;
    const int sw = l15 & 7;

    f32x4 acc[3][2][4];
#pragma unroll
    for (int wh = 0; wh < 3; ++wh)
#pragma unroll
        for (int rs = 0; rs < 2; ++rs)
#pragma unroll
            for (int t = 0; t < 4; ++t) acc[wh][rs][t] = (f32x4){0.f, 0.f, 0.f, 0.f};

    const int arow = tid >> 1, acg = (tid & 1) * 4;     // A: row, granule base
    const int brow = tid & 63, bgrp = tid >> 6;         // B: row, 6 granule-cols
    const float* srcA = h + (size_t)(m0 + arow) * IN_DIM;

    float4 aF[8];
    uint4  bF[6];
#pragma unroll
    for (int g = 0; g < 4; ++g) {
        aF[2 * g]     = *(const float4*)(srcA + (acg + g) * 8);
        aF[2 * g + 1] = *(const float4*)(srcA + (acg + g) * 8 + 4);
    }
#pragma unroll
    for (int i = 0; i < 6; ++i) {
        const int gc = bgrp * 6 + i, wh = gc >> 3, c8 = gc & 7;
        bF[i] = *(const uint4*)(Wt + (size_t)wh * HD * IN_DIM +
                                (size_t)(n0 + brow) * IN_DIM + c8 * 8);
    }

    for (int kk = 0; kk < IN_DIM; kk += 64) {
        __syncthreads();
        // ---- stage A: fp32 -> bf16, XOR-swizzled granules ----
#pragma unroll
        for (int g = 0; g < 4; ++g) {
            uint4 u;
            u.x = cvtpk(aF[2 * g].x, aF[2 * g].y);
            u.y = cvtpk(aF[2 * g].z, aF[2 * g].w);
            u.z = cvtpk(aF[2 * g + 1].x, aF[2 * g + 1].y);
            u.w = cvtpk(aF[2 * g + 1].z, aF[2 * g + 1].w);
            *(uint4*)&As[arow * 64 + (((acg + g) ^ (arow & 7)) * 8)] = u;
        }
#pragma unroll
        for (int i = 0; i < 6; ++i) {
            const int gc = bgrp * 6 + i, wh = gc >> 3, c8 = gc & 7;
            *(uint4*)&Bs[wh * 4096 + brow * 64 + ((c8 ^ (brow & 7)) * 8)] = bF[i];
        }
        __syncthreads();
        // ---- prefetch next k-tile into regs (hidden under MFMA) ----
        if (kk + 64 < IN_DIM) {
#pragma unroll
            for (int g = 0; g < 4; ++g) {
                aF[2 * g]     = *(const float4*)(srcA + kk + 64 + (acg + g) * 8);
                aF[2 * g + 1] = *(const float4*)(srcA + kk + 64 + (acg + g) * 8 + 4);
            }
#pragma unroll
            for (int i = 0; i < 6; ++i) {
                const int gc = bgrp * 6 + i, wh = gc >> 3, c8 = gc & 7;
                bF[i] = *(const uint4*)(Wt + (size_t)wh * HD * IN_DIM +
                                        (size_t)(n0 + brow) * IN_DIM + kk + 64 + c8 * 8);
            }
        }
        bf16x8 a[2][2];
#pragma unroll
        for (int rs = 0; rs < 2; ++rs) {
            const int ra = (w * 32 + rs * 16 + l15) * 64;
            a[rs][0] = *(const bf16x8*)&As[ra + ((quad ^ sw) * 8)];
            a[rs][1] = *(const bf16x8*)&As[ra + (((4 + quad) ^ sw) * 8)];
        }
#pragma unroll
        for (int t = 0; t < 4; ++t) {
            const int rb = (t * 16 + l15) * 64;
#pragma unroll
            for (int wh = 0; wh < 3; ++wh) {
                bf16x8 b0 = *(const bf16x8*)&Bs[wh * 4096 + rb + ((quad ^ sw) * 8)];
                bf16x8 b1 = *(const bf16x8*)&Bs[wh * 4096 + rb + (((4 + quad) ^ sw) * 8)];
#pragma unroll
                for (int rs = 0; rs < 2; ++rs) {
                    acc[wh][rs][t] = __builtin_amdgcn_mfma_f32_16x16x32_bf16(a[rs][0], b0, acc[wh][rs][t], 0, 0, 0);
                    acc[wh][rs][t] = __builtin_amdgcn_mfma_f32_16x16x32_bf16(a[rs][1], b1, acc[wh][rs][t], 0, 0, 0);
                }
            }
        }
    }

    // ---- Q and K epilogues: LDS re-tile, full-line coalesced stores ----
    for (int which = 0; which < 2; ++which) {
        u16* T = pool;   // [128][72]
        const float* bias = (which == 0) ? bq : bk;
        u16* Out = (which == 0) ? Qg : Kg;
        const float scale = (which == 0) ? QSCALE : 1.0f;
        __syncthreads();
#pragma unroll
        for (int t = 0; t < 4; ++t) {
            const float bvv = bias[n0 + t * 16 + l15];
#pragma unroll
            for (int rs = 0; rs < 2; ++rs) {
                const int rowb = w * 32 + rs * 16 + quad * 4;
#pragma unroll
                for (int r = 0; r < 4; ++r)
                    T[(rowb + r) * 72 + t * 16 + l15] =
                        f2bf((acc[which][rs][t][r] + bvv) * scale);
            }
        }
        __syncthreads();
        const int row = tid >> 1, half = tid & 1;
        u16* dst = Out + (size_t)(m0 + row) * HD + n0 + half * 32;
        const u16* srcT = &T[row * 72 + half * 32];
#pragma unroll
        for (int i = 0; i < 4; ++i)
            *(uint4*)(dst + i * 8) = *(const uint4*)(srcT + i * 8);
    }

    // ---- V epilogue: transpose + per-64-chunk permutation ----
    {
        u16* T = pool;   // [64][136]
        __syncthreads();
#pragma unroll
        for (int t = 0; t < 4; ++t) {
            const float bvv = bv[n0 + t * 16 + l15];
            const int trow = (t * 16 + l15) * 136;
#pragma unroll
            for (int rs = 0; rs < 2; ++rs) {
                const int base = w * 32 + rs * 16 + quad * 4;   // mult of 4
                const int c64 = base >> 6;
                const int mloc = base & 63;
                const int cb = c64 * 64 + ((mloc & 15) * 4) + (mloc >> 4);
#pragma unroll
                for (int r = 0; r < 4; ++r)
                    T[trow + cb + 4 * r] = f2bf(acc[2][rs][t][r] + bvv);
            }
        }
        __syncthreads();
        const int b = m0 >> 10, nloc = m0 & 1023;
        const int d = tid >> 2, c = (tid & 3) * 32;
        u16* dst = Vtg + ((size_t)(b * NHEADS + hh) * DH + d) * NSEQ + nloc + c;
#pragma unroll
        for (int i = 0; i < 4; ++i)
            *(uint4*)(dst + i * 8) = *(uint4*)&T[d * 136 + c + i * 8];
    }
}

// ============================================================
// Fused masked attention, no-max softmax, 32 q-rows per wave:
// grid (8 q-tiles of 128, 64 b*h), 256 threads (4 waves x 2 rowgrps).
// K/V LDS fragments read ONCE per chunk, reused across both
// row-groups (halves LDS read traffic per unit work vs R7).
// ============================================================
__global__ __launch_bounds__(256, 3)
void attn_kernel(const u16* __restrict__ MaddT, const u16* __restrict__ Qg,
                 const u16* __restrict__ Kg, const u16* __restrict__ Vtg,
                 float* __restrict__ out)
{
    __shared__ u16 Ks[2][64 * 64];
    __shared__ u16 Vs[2][64 * 64];     // [d][pos]  (keys permuted per chunk)
    __shared__ u16 Ps[128 * 64];       // [q][pos], XOR-swizzled 16B granules

    const int tid = threadIdx.x;
    const int w = tid >> 6, lane = tid & 63, l15 = lane & 15, quad = lane >> 4;
    const int qt = blockIdx.x, bh = blockIdx.y;
    const int b = bh >> 3;
    const int n0 = qt * 128;
    const size_t rowbase = (size_t)b * NSEQ;
    const int colbase = (bh & 7) * DH;
    const int sw = l15 & 7;

    // Q A-frags for 2 row-groups (bf16, pre-scaled by 0.125*log2e)
    bf16x8 qa[2][2];
#pragma unroll
    for (int rs = 0; rs < 2; ++rs) {
        const u16* qrow = Qg + (rowbase + n0 + w * 32 + rs * 16 + l15) * HD + colbase;
        qa[rs][0] = *(const bf16x8*)(qrow + quad * 8);
        qa[rs][1] = *(const bf16x8*)(qrow + 32 + quad * 8);
    }

    // staging: 256 thr -> 64 rows x 4 granule-pairs (32B/thread each of K,V)
    const int srow = tid >> 2, cp = (tid & 3) * 2;
    const int swc0 = ((cp ^ (srow & 7)) * 8), swc1 = (((cp + 1) ^ (srow & 7)) * 8);
    const u16* kgp = Kg + (rowbase + srow) * HD + colbase + cp * 8;
    const u16* vgp = Vtg + ((size_t)bh * DH + srow) * NSEQ + cp * 8;
    // mask adds: MaddT[key][q]; key = ch*64 + t*16 + l15, q = n0+w*32+rs*16+quad*4+r
    const u16* mgp = MaddT + (size_t)l15 * NSEQ + n0 + w * 32 + quad * 4;

    uint4 kG0 = *(const uint4*)kgp, kG1 = *(const uint4*)(kgp + 8);
    uint4 vG0 = *(const uint4*)vgp, vG1 = *(const uint4*)(vgp + 8);
    ushort4 mG[2][4];
#pragma unroll
    for (int rs = 0; rs < 2; ++rs)
#pragma unroll
        for (int t = 0; t < 4; ++t)
            mG[rs][t] = *(const ushort4*)(mgp + (size_t)(t * 16) * NSEQ + rs * 16);

    *(uint4*)&Ks[0][srow * 64 + swc0] = kG0;
    *(uint4*)&Ks[0][srow * 64 + swc1] = kG1;
    *(uint4*)&Vs[0][srow * 64 + swc0] = vG0;
    *(uint4*)&Vs[0][srow * 64 + swc1] = vG1;
    __syncthreads();

    float lrow[2][4] = {{0.f, 0.f, 0.f, 0.f}, {0.f, 0.f, 0.f, 0.f}};
    f32x4 O[2][4];
#pragma unroll
    for (int rs = 0; rs < 2; ++rs)
#pragma unroll
        for (int t = 0; t < 4; ++t) O[rs][t] = (f32x4){0.f, 0.f, 0.f, 0.f};

    for (int ch = 0; ch < 16; ++ch) {
        const int cur = ch & 1;

        // C-init from mask adds (current chunk)
        f32x4 s4[2][4];
#pragma unroll
        for (int rs = 0; rs < 2; ++rs)
#pragma unroll
            for (int t = 0; t < 4; ++t)
                s4[rs][t] = (f32x4){bf2f(mG[rs][t].x), bf2f(mG[rs][t].y),
                                    bf2f(mG[rs][t].z), bf2f(mG[rs][t].w)};

        // prefetch next chunk into regs (overlaps MFMA)
        if (ch < 15) {
            kG0 = *(const uint4*)(kgp + (size_t)(ch + 1) * 64 * HD);
            kG1 = *(const uint4*)(kgp + (size_t)(ch + 1) * 64 * HD + 8);
            vG0 = *(const uint4*)(vgp + (ch + 1) * 64);
            vG1 = *(const uint4*)(vgp + (ch + 1) * 64 + 8);
#pragma unroll
            for (int rs = 0; rs < 2; ++rs)
#pragma unroll
                for (int t = 0; t < 4; ++t)
                    mG[rs][t] = *(const ushort4*)(mgp + ((size_t)(ch + 1) * 64 + t * 16) * NSEQ + rs * 16);
        }

        // S(log2) = Q K^T + mask — K frags read once, used by both rowgrps
#pragma unroll
        for (int t = 0; t < 4; ++t) {
            const int rb = (t * 16 + l15) * 64;
            bf16x8 kb0 = *(const bf16x8*)&Ks[cur][rb + ((quad ^ sw) * 8)];
            bf16x8 kb1 = *(const bf16x8*)&Ks[cur][rb + (((4 + quad) ^ sw) * 8)];
#pragma unroll
            for (int rs = 0; rs < 2; ++rs) {
                s4[rs][t] = __builtin_amdgcn_mfma_f32_16x16x32_bf16(qa[rs][0], kb0, s4[rs][t], 0, 0, 0);
                s4[rs][t] = __builtin_amdgcn_mfma_f32_16x16x32_bf16(qa[rs][1], kb1, s4[rs][t], 0, 0, 0);
            }
        }

        if (ch < 15) {
            *(uint4*)&Ks[1 - cur][srow * 64 + swc0] = kG0;
            *(uint4*)&Ks[1 - cur][srow * 64 + swc1] = kG1;
            *(uint4*)&Vs[1 - cur][srow * 64 + swc0] = vG0;
            *(uint4*)&Vs[1 - cur][srow * 64 + swc1] = vG1;
        }

        // p = exp2(s); pack pairs; one b64 store per row
#pragma unroll
        for (int rs = 0; rs < 2; ++rs)
#pragma unroll
            for (int r = 0; r < 4; ++r) {
                float p0 = EXP2(s4[rs][0][r]);
                float p1 = EXP2(s4[rs][1][r]);
                float p2 = EXP2(s4[rs][2][r]);
                float p3 = EXP2(s4[rs][3][r]);
                lrow[rs][r] += (p0 + p1) + (p2 + p3);
                uint2 pw;
                pw.x = cvtpk(p0, p1);
                pw.y = cvtpk(p2, p3);
                const int q7 = (quad * 4 + r) & 7;
                *(uint2*)&Ps[(w * 32 + rs * 16 + quad * 4 + r) * 64 +
                             (((l15 >> 1) ^ q7) * 8) + (l15 & 1) * 4] = pw;
            }

        // O += P V  (wave-private Ps rows; V frags shared across rowgrps)
        {
            bf16x8 pa[2][2];
#pragma unroll
            for (int rs = 0; rs < 2; ++rs) {
                const int par = (w * 32 + rs * 16 + l15) * 64;
                pa[rs][0] = *(const bf16x8*)&Ps[par + ((quad ^ sw) * 8)];
                pa[rs][1] = *(const bf16x8*)&Ps[par + (((4 + quad) ^ sw) * 8)];
            }
#pragma unroll
            for (int t = 0; t < 4; ++t) {
                const int rb = (t * 16 + l15) * 64;
                bf16x8 vb0 = *(const bf16x8*)&Vs[cur][rb + ((quad ^ sw) * 8)];
                bf16x8 vb1 = *(const bf16x8*)&Vs[cur][rb + (((4 + quad) ^ sw) * 8)];
#pragma unroll
                for (int rs = 0; rs < 2; ++rs) {
                    O[rs][t] = __builtin_amdgcn_mfma_f32_16x16x32_bf16(pa[rs][0], vb0, O[rs][t], 0, 0, 0);
                    O[rs][t] = __builtin_amdgcn_mfma_f32_16x16x32_bf16(pa[rs][1], vb1, O[rs][t], 0, 0, 0);
                }
            }
        }
        __syncthreads();
    }

    // l across the 16 column-lanes
#pragma unroll
    for (int d = 1; d < 16; d <<= 1)
#pragma unroll
        for (int rs = 0; rs < 2; ++rs)
#pragma unroll
            for (int r = 0; r < 4; ++r)
                lrow[rs][r] += __shfl_xor(lrow[rs][r], d, 64);

#pragma unroll
    for (int rs = 0; rs < 2; ++rs) {
        float inv[4];
#pragma unroll
        for (int r = 0; r < 4; ++r) inv[r] = 1.0f / lrow[rs][r];
#pragma unroll
        for (int t = 0; t < 4; ++t)
#pragma unroll
            for (int r = 0; r < 4; ++r)
                out[(rowbase + n0 + w * 32 + rs * 16 + quad * 4 + r) * HD +
                    colbase + t * 16 + l15] = O[rs][t][r] * inv[r];
    }
}

// ============================================================
extern "C" void kernel_launch(void* const* d_in, const int* in_sizes, int n_in,
                              void* d_out, int out_size, void* d_ws, size_t ws_size,
                              hipStream_t stream) {
    const int*   adj = (const int*)d_in[0];
    const float* h   = (const float*)d_in[1];
    const float* Wq  = (const float*)d_in[2];
    const float* bq  = (const float*)d_in[3];
    const float* Wk  = (const float*)d_in[4];
    const float* bk  = (const float*)d_in[5];
    const float* Wv  = (const float*)d_in[6];
    const float* bv  = (const float*)d_in[7];
    float* outp = (float*)d_out;

    u16* Wt    = (u16*)d_ws;                                 // 3*512*256
    u16* Qg    = Wt + (size_t)3 * HD * IN_DIM;               // 4 Mi u16 each
    u16* Kg    = Qg + (size_t)BATCH * NSEQ * HD;
    u16* Vtg   = Kg + (size_t)BATCH * NSEQ * HD;
    u16* MaddT = Vtg + (size_t)BATCH * NSEQ * HD;            // 1 Mi u16

    prep_kernel<<<352, 256, 0, stream>>>(Wq, Wk, Wv, adj, Wt, MaddT);
    qkv_gemm_kernel<<<dim3(BATCH * NSEQ / 128, NHEADS), 256, 0, stream>>>(
        h, Wt, bq, bk, bv, Qg, Kg, Vtg);
    attn_kernel<<<dim3(NSEQ / 128, BATCH * NHEADS), 256, 0, stream>>>(
        MaddT, Qg, Kg, Vtg, outp);
}

// Round 9
// 140.896 us; speedup vs baseline: 1.1266x; 1.1266x over previous
//
#include <hip/hip_runtime.h>
#include <hip/hip_bf16.h>
#include <math.h>

#define IN_DIM 256
#define HD     512   // NUM_HEADS * OUT_DIM
#define NHEADS 8
#define DH     64
#define NSEQ   1024
#define BATCH  8

#define QSCALE  0.18033688011112042f   // 0.125 * log2(e): S in log2 domain
#define MASKVAL -3.0e38f

typedef unsigned short u16;
typedef unsigned int   u32;
typedef short bf16x8 __attribute__((ext_vector_type(8)));
typedef float f32x4  __attribute__((ext_vector_type(4)));

#if __has_builtin(__builtin_amdgcn_exp2f)
#define EXP2(x) __builtin_amdgcn_exp2f(x)
#else
#define EXP2(x) __expf(0.69314718056f * (x))
#endif

static __device__ __forceinline__ u16 f2bf(float x) {
    u32 u = __builtin_bit_cast(u32, x);
    u += 0x7FFFu + ((u >> 16) & 1u);     // RNE
    return (u16)(u >> 16);
}
static __device__ __forceinline__ u32 pk(u16 a, u16 b) {
    return (u32)a | ((u32)b << 16);
}
static __device__ __forceinline__ u32 cvtpk(float a, float b) {
    __hip_bfloat162 t = __float22bfloat162_rn(make_float2(a, b));
    u32 r; __builtin_memcpy(&r, &t, 4);
    return r;
}

// ============================================================
// Prep (352 blocks):
//  blocks [0,96):   W [K=256][N=512] fp32 -> Wt [N][K] bf16 (x3)
//  blocks [96,352): adj -> MaddF[key][q] fp32 {0, -3e38}
// ============================================================
__global__ __launch_bounds__(256)
void prep_kernel(const float* __restrict__ Wq, const float* __restrict__ Wk,
                 const float* __restrict__ Wv, const int* __restrict__ adj,
                 u16* __restrict__ Wt, float* __restrict__ MaddF)
{
    __shared__ u32 shpool[64 * 65];
    const int bid = blockIdx.x, tid = threadIdx.x;

    if (bid < 96) {
        // ---- weight transpose ----
        float* tile = (float*)shpool;        // [64][65]
        const int wk = bid;
        const int k0 = (wk & 3) * 64, n0 = ((wk >> 2) & 7) * 64, wsel = wk >> 5;
        const float* W = (wsel == 0) ? Wq : (wsel == 1) ? Wk : Wv;
        u16* Out = Wt + (size_t)wsel * HD * IN_DIM;

        const int r = tid >> 2, c0 = (tid & 3) * 16;
#pragma unroll
        for (int j = 0; j < 16; j += 4) {
            float4 v = *(const float4*)(W + (size_t)(k0 + r) * HD + n0 + c0 + j);
            tile[r * 65 + c0 + j + 0] = v.x; tile[r * 65 + c0 + j + 1] = v.y;
            tile[r * 65 + c0 + j + 2] = v.z; tile[r * 65 + c0 + j + 3] = v.w;
        }
        __syncthreads();
        const int n = tid >> 2, ks = (tid & 3) * 16;
        u16 o[16];
#pragma unroll
        for (int j = 0; j < 16; ++j) o[j] = f2bf(tile[(ks + j) * 65 + n]);
        uint4 u0, u1;
        u0.x = pk(o[0], o[1]);   u0.y = pk(o[2], o[3]);
        u0.z = pk(o[4], o[5]);   u0.w = pk(o[6], o[7]);
        u1.x = pk(o[8], o[9]);   u1.y = pk(o[10], o[11]);
        u1.z = pk(o[12], o[13]); u1.w = pk(o[14], o[15]);
        u16* dst = Out + (size_t)(n0 + n) * IN_DIM + k0 + ks;
        *(uint4*)(dst) = u0;
        *(uint4*)(dst + 8) = u1;
    } else {
        // ---- adjacency transpose to fp32 additive mask ----
        int* tile = (int*)shpool;            // [64][65]
        const int abid = bid - 96;
        const int tR = abid >> 4, tC = abid & 15;   // q-tile, k-tile
        const int r = tid >> 2, cg = (tid & 3) * 16;
        const int* src = adj + (size_t)(tR * 64 + r) * NSEQ + tC * 64 + cg;
#pragma unroll
        for (int j = 0; j < 16; j += 4) {
            int4 a = *(const int4*)(src + j);
            tile[r * 65 + cg + j + 0] = a.x; tile[r * 65 + cg + j + 1] = a.y;
            tile[r * 65 + cg + j + 2] = a.z; tile[r * 65 + cg + j + 3] = a.w;
        }
        __syncthreads();
        const int kk = tid >> 2, qg = (tid & 3) * 16;
        float* dst = MaddF + (size_t)(tC * 64 + kk) * NSEQ + tR * 64 + qg;
#pragma unroll
        for (int j = 0; j < 16; j += 4) {
            float4 o;
            o.x = (tile[(qg + j + 0) * 65 + kk] == 0) ? MASKVAL : 0.f;
            o.y = (tile[(qg + j + 1) * 65 + kk] == 0) ? MASKVAL : 0.f;
            o.z = (tile[(qg + j + 2) * 65 + kk] == 0) ? MASKVAL : 0.f;
            o.w = (tile[(qg + j + 3) * 65 + kk] == 0) ? MASKVAL : 0.f;
            *(float4*)(dst + j) = o;
        }
    }
}

// ============================================================
// Fused QKV GEMM: grid (128 m-tiles of 64, 8 heads), 256 thr.
// BM=64: acc = 48 VGPR -> 4+ blocks/CU for latency hiding.
// A (fp32 h -> bf16) staged once/k-step; 3 B-tiles; 24 MFMA/wave/k.
// Q pre-scaled by QSCALE; V transposed+chunk-permuted:
// Vt[b][h][d][ch*64+pos(m)], pos(m) = (m&15)*4 + (m>>4).
// ============================================================
__global__ __launch_bounds__(256, 4)
void qkv_gemm_kernel(const float* __restrict__ h, const u16* __restrict__ Wt,
                     const float* __restrict__ bq, const float* __restrict__ bk,
                     const float* __restrict__ bv,
                     u16* __restrict__ Qg, u16* __restrict__ Kg,
                     u16* __restrict__ Vtg)
{
    __shared__ u16 pool[64 * 64 + 3 * 64 * 64];   // As | Bs[3]; epilogue reuse
    u16* As = pool;
    u16* Bs = pool + 64 * 64;

    const int m0 = blockIdx.x * 64;
    const int hh = blockIdx.y;
    const int n0 = hh * 64;

    const int tid = threadIdx.x;
    const int w = tid >> 6, lane = tid & 63, l15 = lane & 15, quad = lane >> 4;
    const int sw = l15 & 7;

    f32x4 acc[3][4];
#pragma unroll
    for (int wh = 0; wh < 3; ++wh)
#pragma unroll
        for (int t = 0; t < 4; ++t) acc[wh][t] = (f32x4){0.f, 0.f, 0.f, 0.f};

    const int arow = tid >> 2, acg = (tid & 3) * 2;     // A: row, 2 granules
    const int brow = tid & 63, bgrp = tid >> 6;         // B: row, 6 granule-cols
    const float* srcA = h + (size_t)(m0 + arow) * IN_DIM;

    for (int kk = 0; kk < IN_DIM; kk += 64) {
        __syncthreads();
        // ---- stage A: fp32 -> bf16, XOR-swizzled granules ----
#pragma unroll
        for (int g = 0; g < 2; ++g) {
            const float* p = srcA + kk + (acg + g) * 8;
            float4 v0 = *(const float4*)(p);
            float4 v1 = *(const float4*)(p + 4);
            uint4 u;
            u.x = cvtpk(v0.x, v0.y); u.y = cvtpk(v0.z, v0.w);
            u.z = cvtpk(v1.x, v1.y); u.w = cvtpk(v1.z, v1.w);
            *(uint4*)&As[arow * 64 + (((acg + g) ^ (arow & 7)) * 8)] = u;
        }
        // ---- stage B: 3 weight tiles (bf16, pre-transposed) ----
#pragma unroll
        for (int i = 0; i < 6; ++i) {
            const int gc = bgrp * 6 + i;            // 0..23
            const int wh = gc >> 3, c8 = gc & 7;
            *(uint4*)&Bs[wh * 4096 + brow * 64 + ((c8 ^ (brow & 7)) * 8)] =
                *(const uint4*)(Wt + (size_t)wh * HD * IN_DIM +
                                (size_t)(n0 + brow) * IN_DIM + kk + c8 * 8);
        }
        __syncthreads();
        const int ra = (w * 16 + l15) * 64;
        bf16x8 a0 = *(const bf16x8*)&As[ra + ((quad ^ sw) * 8)];
        bf16x8 a1 = *(const bf16x8*)&As[ra + (((4 + quad) ^ sw) * 8)];
#pragma unroll
        for (int t = 0; t < 4; ++t) {
            const int rb = (t * 16 + l15) * 64;
#pragma unroll
            for (int wh = 0; wh < 3; ++wh) {
                bf16x8 b0 = *(const bf16x8*)&Bs[wh * 4096 + rb + ((quad ^ sw) * 8)];
                bf16x8 b1 = *(const bf16x8*)&Bs[wh * 4096 + rb + (((4 + quad) ^ sw) * 8)];
                acc[wh][t] = __builtin_amdgcn_mfma_f32_16x16x32_bf16(a0, b0, acc[wh][t], 0, 0, 0);
                acc[wh][t] = __builtin_amdgcn_mfma_f32_16x16x32_bf16(a1, b1, acc[wh][t], 0, 0, 0);
            }
        }
    }

    // ---- Q and K epilogues: LDS re-tile, full-line coalesced stores ----
    for (int which = 0; which < 2; ++which) {
        u16* T = pool;   // [64][72]
        const float* bias = (which == 0) ? bq : bk;
        u16* Out = (which == 0) ? Qg : Kg;
        const float scale = (which == 0) ? QSCALE : 1.0f;
        __syncthreads();
#pragma unroll
        for (int t = 0; t < 4; ++t) {
            const float bvv = bias[n0 + t * 16 + l15];
            const int rowb = w * 16 + quad * 4;
#pragma unroll
            for (int r = 0; r < 4; ++r)
                T[(rowb + r) * 72 + t * 16 + l15] =
                    f2bf((acc[which][t][r] + bvv) * scale);
        }
        __syncthreads();
        const int row = tid >> 2, qc = (tid & 3) * 16;
        u16* dst = Out + (size_t)(m0 + row) * HD + n0 + qc;
        const u16* srcT = &T[row * 72 + qc];
        *(uint4*)(dst)     = *(const uint4*)(srcT);
        *(uint4*)(dst + 8) = *(const uint4*)(srcT + 8);
    }

    // ---- V epilogue: transpose + chunk permutation (BM=64 = 1 chunk) ----
    {
        u16* T = pool;   // [64][72]
        __syncthreads();
#pragma unroll
        for (int t = 0; t < 4; ++t) {
            const float bvv = bv[n0 + t * 16 + l15];
            const int trow = (t * 16 + l15) * 72;
#pragma unroll
            for (int r = 0; r < 4; ++r)
                T[trow + (quad * 4 + r) * 4 + w] = f2bf(acc[2][t][r] + bvv);
        }
        __syncthreads();
        const int b = m0 >> 10, nloc = m0 & 1023;
        const int d = tid >> 2, c = (tid & 3) * 16;
        u16* dst = Vtg + ((size_t)(b * NHEADS + hh) * DH + d) * NSEQ + nloc + c;
        *(uint4*)(dst)     = *(uint4*)&T[d * 72 + c];
        *(uint4*)(dst + 8) = *(uint4*)&T[d * 72 + c + 8];
    }
}

// ============================================================
// Fused masked attention, no-max softmax (R7 structure):
// grid (64 b*h, 8 q-tiles) — bh fastest so the 8 qt-blocks of one
// head land on ONE XCD (K/V L2 reuse; R7 had them on 8 XCDs).
// 512 threads (8 waves x 16 q-rows); fp32 mask C-init.
// ============================================================
__global__ __launch_bounds__(512, 4)
void attn_kernel(const float* __restrict__ MaddF, const u16* __restrict__ Qg,
                 const u16* __restrict__ Kg, const u16* __restrict__ Vtg,
                 float* __restrict__ out)
{
    __shared__ u16 Ks[2][64 * 64];
    __shared__ u16 Vs[2][64 * 64];     // [d][pos]  (keys permuted per chunk)
    __shared__ u16 Ps[128 * 64];       // [q][pos], XOR-swizzled 16B granules

    const int tid = threadIdx.x;
    const int w = tid >> 6, lane = tid & 63, l15 = lane & 15, quad = lane >> 4;
    const int bh = blockIdx.x, qt = blockIdx.y;
    const int b = bh >> 3;
    const int n0 = qt * 128;
    const size_t rowbase = (size_t)b * NSEQ;
    const int colbase = (bh & 7) * DH;
    const int sw = l15 & 7;

    // Q A-frags (bf16, pre-scaled by 0.125*log2e)
    const u16* qrow = Qg + (rowbase + n0 + w * 16 + l15) * HD + colbase;
    const bf16x8 qa0 = *(const bf16x8*)(qrow + quad * 8);
    const bf16x8 qa1 = *(const bf16x8*)(qrow + 32 + quad * 8);

    // staging: 512 thr -> 64 rows x 8 granules of 8 u16
    const int srow = tid >> 3, c8w = tid & 7;
    const int swc = ((c8w ^ (srow & 7)) * 8);
    const u16* kgp = Kg + (rowbase + srow) * HD + colbase + c8w * 8;
    const u16* vgp = Vtg + ((size_t)bh * DH + srow) * NSEQ + c8w * 8;
    // fp32 mask adds: MaddF[key][q]; key = ch*64+t*16+l15, q = n0+w*16+quad*4+r
    const float* mgp = MaddF + (size_t)l15 * NSEQ + n0 + w * 16 + quad * 4;

    uint4 kG = *(const uint4*)kgp;
    uint4 vG = *(const uint4*)vgp;
    float4 mG[4];
#pragma unroll
    for (int t = 0; t < 4; ++t) mG[t] = *(const float4*)(mgp + (size_t)(t * 16) * NSEQ);

    *(uint4*)&Ks[0][srow * 64 + swc] = kG;
    *(uint4*)&Vs[0][srow * 64 + swc] = vG;
    __syncthreads();

    float lrow[4] = {0.f, 0.f, 0.f, 0.f};
    f32x4 O[4];
#pragma unroll
    for (int t = 0; t < 4; ++t) O[t] = (f32x4){0.f, 0.f, 0.f, 0.f};

    const int pwbase = (w * 16 + quad * 4) * 64;
    const int parow  = (w * 16 + l15) * 64;

    for (int ch = 0; ch < 16; ++ch) {
        const int cur = ch & 1;

        // C-init from fp32 mask adds (current chunk)
        f32x4 s4[4];
#pragma unroll
        for (int t = 0; t < 4; ++t)
            s4[t] = (f32x4){mG[t].x, mG[t].y, mG[t].z, mG[t].w};

        // prefetch next chunk into regs (overlaps MFMA)
        if (ch < 15) {
            kG = *(const uint4*)(kgp + (size_t)(ch + 1) * 64 * HD);
            vG = *(const uint4*)(vgp + (ch + 1) * 64);
#pragma unroll
            for (int t = 0; t < 4; ++t)
                mG[t] = *(const float4*)(mgp + ((size_t)(ch + 1) * 64 + t * 16) * NSEQ);
        }

        // S(log2) = Q K^T + mask
#pragma unroll
        for (int t = 0; t < 4; ++t) {
            const int rb = (t * 16 + l15) * 64;
            bf16x8 kb0 = *(const bf16x8*)&Ks[cur][rb + ((quad ^ sw) * 8)];
            bf16x8 kb1 = *(const bf16x8*)&Ks[cur][rb + (((4 + quad) ^ sw) * 8)];
            s4[t] = __builtin_amdgcn_mfma_f32_16x16x32_bf16(qa0, kb0, s4[t], 0, 0, 0);
            s4[t] = __builtin_amdgcn_mfma_f32_16x16x32_bf16(qa1, kb1, s4[t], 0, 0, 0);
        }

        if (ch < 15) {
            *(uint4*)&Ks[1 - cur][srow * 64 + swc] = kG;
            *(uint4*)&Vs[1 - cur][srow * 64 + swc] = vG;
        }

        // p = exp2(s); pack pairs; one b64 store per row
#pragma unroll
        for (int r = 0; r < 4; ++r) {
            float p0 = EXP2(s4[0][r]);
            float p1 = EXP2(s4[1][r]);
            float p2 = EXP2(s4[2][r]);
            float p3 = EXP2(s4[3][r]);
            lrow[r] += (p0 + p1) + (p2 + p3);
            uint2 pw;
            pw.x = cvtpk(p0, p1);
            pw.y = cvtpk(p2, p3);
            const int q7 = (quad * 4 + r) & 7;
            *(uint2*)&Ps[pwbase + r * 64 + (((l15 >> 1) ^ q7) * 8) + (l15 & 1) * 4] = pw;
        }

        // O += P V  (wave-private Ps rows: no barrier)
        {
            bf16x8 pa0 = *(const bf16x8*)&Ps[parow + ((quad ^ sw) * 8)];
            bf16x8 pa1 = *(const bf16x8*)&Ps[parow + (((4 + quad) ^ sw) * 8)];
#pragma unroll
            for (int t = 0; t < 4; ++t) {
                const int rb = (t * 16 + l15) * 64;
                bf16x8 vb0 = *(const bf16x8*)&Vs[cur][rb + ((quad ^ sw) * 8)];
                bf16x8 vb1 = *(const bf16x8*)&Vs[cur][rb + (((4 + quad) ^ sw) * 8)];
                O[t] = __builtin_amdgcn_mfma_f32_16x16x32_bf16(pa0, vb0, O[t], 0, 0, 0);
                O[t] = __builtin_amdgcn_mfma_f32_16x16x32_bf16(pa1, vb1, O[t], 0, 0, 0);
            }
        }
        __syncthreads();
    }

    // l across the 16 column-lanes
#pragma unroll
    for (int d = 1; d < 16; d <<= 1)
#pragma unroll
        for (int r = 0; r < 4; ++r)
            lrow[r] += __shfl_xor(lrow[r], d, 64);

    float inv[4];
#pragma unroll
    for (int r = 0; r < 4; ++r) inv[r] = 1.0f / lrow[r];
#pragma unroll
    for (int t = 0; t < 4; ++t)
#pragma unroll
        for (int r = 0; r < 4; ++r)
            out[(rowbase + n0 + w * 16 + quad * 4 + r) * HD + colbase + t * 16 + l15] =
                O[t][r] * inv[r];
}

// ============================================================
extern "C" void kernel_launch(void* const* d_in, const int* in_sizes, int n_in,
                              void* d_out, int out_size, void* d_ws, size_t ws_size,
                              hipStream_t stream) {
    const int*   adj = (const int*)d_in[0];
    const float* h   = (const float*)d_in[1];
    const float* Wq  = (const float*)d_in[2];
    const float* bq  = (const float*)d_in[3];
    const float* Wk  = (const float*)d_in[4];
    const float* bk  = (const float*)d_in[5];
    const float* Wv  = (const float*)d_in[6];
    const float* bv  = (const float*)d_in[7];
    float* outp = (float*)d_out;

    u16* Wt     = (u16*)d_ws;                                // 3*512*256 u16
    u16* Qg     = Wt + (size_t)3 * HD * IN_DIM;              // 4 Mi u16 each
    u16* Kg     = Qg + (size_t)BATCH * NSEQ * HD;
    u16* Vtg    = Kg + (size_t)BATCH * NSEQ * HD;
    float* MaddF = (float*)(Vtg + (size_t)BATCH * NSEQ * HD);  // 1 Mi f32

    prep_kernel<<<352, 256, 0, stream>>>(Wq, Wk, Wv, adj, Wt, MaddF);
    qkv_gemm_kernel<<<dim3(BATCH * NSEQ / 64, NHEADS), 256, 0, stream>>>(
        h, Wt, bq, bk, bv, Qg, Kg, Vtg);
    attn_kernel<<<dim3(BATCH * NHEADS, NSEQ / 128), 512, 0, stream>>>(
        MaddF, Qg, Kg, Vtg, outp);
}